// Round 14
// baseline (182.790 us; speedup 1.0000x reference)
//
#include <hip/hip_runtime.h>
#include <hip/hip_bf16.h>
#include <math.h>

#define HIDDEN 512
#define NHEADS 8
#define HDIM 64
#define SLEN 2048
#define BATCH 4
#define NROWS (BATCH*SLEN)   /* 8192 */
#define RTAB (2*SLEN-1)      /* 4095 */
#define LOG2E 1.44269504088896340736f
#define SCALE_L2E (0.125f * LOG2E)

typedef _Float16 f16;
typedef f16 f16x8 __attribute__((ext_vector_type(8)));
typedef float f32x4 __attribute__((ext_vector_type(4)));
typedef unsigned short u16;
typedef unsigned int u32;
typedef u16 u16x4 __attribute__((ext_vector_type(4)));
typedef u16 u16x8 __attribute__((ext_vector_type(8)));
typedef u32 u32x4 __attribute__((ext_vector_type(4)));

// ---------------------------------------------------------------------------
// Kernel 1: relative-position bias biasrel[h][t-s+2047], pre-scaled by log2e.
// ---------------------------------------------------------------------------
__global__ __launch_bounds__(256) void bias_precompute(
    const float* __restrict__ bias_table, float* __restrict__ biasrel) {
  int i = blockIdx.x * 256 + threadIdx.x;
  if (i >= NHEADS * RTAB) return;
  int h = i / RTAB;
  int idx = i - h * RTAB;
  int rel = idx - (SLEN - 1);
  int ret = rel > 0 ? 16 : 0;
  int a = rel < 0 ? -rel : rel;
  int bidx;
  if (a < 8) {
    bidx = a;
  } else {
    float val = logf((float)a * 0.125f) / logf(16.0f) * 8.0f;
    bidx = 8 + (int)val;
    if (bidx > 15) bidx = 15;
  }
  biasrel[i] = bias_table[(ret + bidx) * NHEADS + h] * LOG2E;
}

// ---------------------------------------------------------------------------
// Kernel 2a: x f32 -> f16
// ---------------------------------------------------------------------------
__global__ __launch_bounds__(256) void conv_x(
    const float* __restrict__ x, u16* __restrict__ xh) {
  int i = blockIdx.x * 256 + threadIdx.x;
  const float4* p = (const float4*)(x + (size_t)i * 8);
  float4 a = p[0], b = p[1];
  u16x8 o;
  f16 t0 = (f16)a.x; o[0] = *(u16*)&t0;
  f16 t1 = (f16)a.y; o[1] = *(u16*)&t1;
  f16 t2 = (f16)a.z; o[2] = *(u16*)&t2;
  f16 t3 = (f16)a.w; o[3] = *(u16*)&t3;
  f16 t4 = (f16)b.x; o[4] = *(u16*)&t4;
  f16 t5 = (f16)b.y; o[5] = *(u16*)&t5;
  f16 t6 = (f16)b.z; o[6] = *(u16*)&t6;
  f16 t7 = (f16)b.w; o[7] = *(u16*)&t7;
  *(u16x8*)(xh + (size_t)i * 8) = o;
}

// ---------------------------------------------------------------------------
// Kernel 2b: weights f32 [k][n] -> f16 transposed [n][k].
// ---------------------------------------------------------------------------
__global__ __launch_bounds__(256) void conv_w(
    const float* __restrict__ Wq, const float* __restrict__ Wk,
    const float* __restrict__ Wv, const float* __restrict__ Wo,
    u16* __restrict__ Wt) {
  const float* W = blockIdx.y == 0 ? Wq : blockIdx.y == 1 ? Wk
                 : blockIdx.y == 2 ? Wv : Wo;
  u16* dst = Wt + (size_t)blockIdx.y * HIDDEN * HIDDEN;
  int t = blockIdx.x * 256 + threadIdx.x;
  int k = t >> 6, n0 = (t & 63) << 3;
  const float4* p = (const float4*)(W + (size_t)k * HIDDEN + n0);
  float4 a = p[0], b = p[1];
  float vals[8] = {a.x, a.y, a.z, a.w, b.x, b.y, b.z, b.w};
#pragma unroll
  for (int j = 0; j < 8; ++j) {
    f16 hv = (f16)vals[j];
    dst[(size_t)(n0 + j) * HIDDEN + k] = *(u16*)&hv;
  }
}

// ---------------------------------------------------------------------------
// Kernel 3: f16 MFMA GEMM (round-11 known-good). mode 0: f32 out (Wo).
// mode 1: z=0 (Q) -> f16 [B,H,S,D] scaled by 0.125*log2e; z=1 (K) same unscaled;
//         z=2 (V) -> f16 [B,H,D,S] sigma-permuted via LDS-transpose epilogue.
// ---------------------------------------------------------------------------
__global__ __launch_bounds__(256) void gemm_mfma(
    const u16* __restrict__ A, const u16* __restrict__ Wt0,
    const u16* __restrict__ Wt1, const u16* __restrict__ Wt2,
    void* __restrict__ O, int mode) {
  __shared__ u16 sm[2 * 128 * 72];
  u16 (*As)[72] = (u16(*)[72])sm;
  u16 (*Bs)[72] = (u16(*)[72])(sm + 128 * 72);
  const u16* Wt = blockIdx.z == 0 ? Wt0 : blockIdx.z == 1 ? Wt1 : Wt2;
  const int tid = threadIdx.x;
  const int w = tid >> 6, l = tid & 63;
  const int lr = l & 15, lg = l >> 4;
  const int wr = w >> 1, wc = w & 1;
  const int m0 = blockIdx.x << 7, n0 = blockIdx.y << 7;
  const int vtmode = (mode == 1) && (blockIdx.z == 2);

  f32x4 acc[4][4] = {};

  u16x8 areg[4], breg[4];
#pragma unroll
  for (int e = 0; e < 4; ++e) {
    int c = (e << 8) + tid;
    int row = c >> 3, g = c & 7;
    areg[e] = *(const u16x8*)(A + (size_t)(m0 + row) * HIDDEN + (g << 3));
    breg[e] = *(const u16x8*)(Wt + (size_t)(n0 + row) * HIDDEN + (g << 3));
  }

  for (int k0 = 0; k0 < HIDDEN; k0 += 64) {
    __syncthreads();
#pragma unroll
    for (int e = 0; e < 4; ++e) {
      int c = (e << 8) + tid;
      int row = c >> 3, g = c & 7;
      *(u16x8*)&As[row][g << 3] = areg[e];
      *(u16x8*)&Bs[row][g << 3] = breg[e];
    }
    __syncthreads();
    if (k0 + 64 < HIDDEN) {
#pragma unroll
      for (int e = 0; e < 4; ++e) {
        int c = (e << 8) + tid;
        int row = c >> 3, g = c & 7;
        areg[e] = *(const u16x8*)(A + (size_t)(m0 + row) * HIDDEN + k0 + 64 + (g << 3));
        breg[e] = *(const u16x8*)(Wt + (size_t)(n0 + row) * HIDDEN + k0 + 64 + (g << 3));
      }
    }
#pragma unroll
    for (int kk = 0; kk < 64; kk += 32) {
      f16x8 af[4], bf[4];
#pragma unroll
      for (int mt = 0; mt < 4; ++mt)
        af[mt] = *(const f16x8*)&As[(wr << 6) + (mt << 4) + lr][kk + (lg << 3)];
#pragma unroll
      for (int nt = 0; nt < 4; ++nt)
        bf[nt] = *(const f16x8*)&Bs[(wc << 6) + (nt << 4) + lr][kk + (lg << 3)];
      if (!vtmode) {
#pragma unroll
        for (int mt = 0; mt < 4; ++mt)
#pragma unroll
          for (int nt = 0; nt < 4; ++nt)
            acc[mt][nt] = __builtin_amdgcn_mfma_f32_16x16x32_f16(
                af[mt], bf[nt], acc[mt][nt], 0, 0, 0);
      } else {
#pragma unroll
        for (int i = 0; i < 4; ++i)
#pragma unroll
          for (int j = 0; j < 4; ++j)
            acc[i][j] = __builtin_amdgcn_mfma_f32_16x16x32_f16(
                bf[i], af[j], acc[i][j], 0, 0, 0);
      }
    }
  }

  if (mode == 0) {
    float* Of = (float*)O;
#pragma unroll
    for (int mt = 0; mt < 4; ++mt)
#pragma unroll
      for (int nt = 0; nt < 4; ++nt)
#pragma unroll
        for (int r = 0; r < 4; ++r) {
          int m = m0 + (wr << 6) + (mt << 4) + (lg << 2) + r;
          int n = n0 + (wc << 6) + (nt << 4) + lr;
          Of[(size_t)m * HIDDEN + n] = acc[mt][nt][r];
        }
  } else if (!vtmode) {
    u16* O16 = (u16*)O + (size_t)blockIdx.z * NROWS * HIDDEN;
    const float osc = (blockIdx.z == 0) ? SCALE_L2E : 1.0f;
#pragma unroll
    for (int mt = 0; mt < 4; ++mt)
#pragma unroll
      for (int nt = 0; nt < 4; ++nt)
#pragma unroll
        for (int r = 0; r < 4; ++r) {
          int m = m0 + (wr << 6) + (mt << 4) + (lg << 2) + r;
          int n = n0 + (wc << 6) + (nt << 4) + lr;
          int b = m >> 11, s = m & (SLEN - 1);
          int h = n >> 6, d = n & 63;
          f16 hv = (f16)(acc[mt][nt][r] * osc);
          O16[(((size_t)b * NHEADS + h) * SLEN + s) * HDIM + d] = *(u16*)&hv;
        }
  } else {
    __syncthreads();
    u16* tt = sm;                           // tile[128][136]: [n_loc][m_loc]
#pragma unroll
    for (int i = 0; i < 4; ++i)
#pragma unroll
      for (int j = 0; j < 4; ++j)
#pragma unroll
        for (int r = 0; r < 4; ++r) {
          int nl = (wc << 6) + (i << 4) + (lg << 2) + r;
          int ml = (wr << 6) + (j << 4) + lr;
          f16 hv = (f16)acc[i][j][r];
          tt[nl * 136 + ml] = *(u16*)&hv;
        }
    __syncthreads();
    u16* O16 = (u16*)O + (size_t)2 * NROWS * HIDDEN;
    int nl = tid >> 1, half = tid & 1;
    int n = n0 + nl;
    int h = n >> 6, d = n & 63;
    int b = m0 >> 11, s_base = m0 & (SLEN - 1);
    u16* orow = O16 + (((size_t)b * NHEADS + h) * HDIM + d) * SLEN + s_base;
    const u16* trow = tt + nl * 136;
#pragma unroll
    for (int c = 0; c < 8; ++c) {
      int v_off = (half << 6) + (c << 3);
      int c0 = (v_off & ~31) | (((v_off >> 3) & 3) << 2);
      u16x4 lo = *(const u16x4*)(trow + c0);
      u16x4 hi = *(const u16x4*)(trow + c0 + 16);
      u16x8 st;
#pragma unroll
      for (int j = 0; j < 4; ++j) { st[j] = lo[j]; st[j + 4] = hi[j]; }
      *(u16x8*)(orow + v_off) = st;
    }
  }
}

// ---------------------------------------------------------------------------
// Kernel 4: flash attention, q x kv 2x2 wave split.
// Wave (wq=w>>1, wk=w&1): wq owns 64 q-rows (4 subtiles), wk owns kv-tile
// parity. Staging/dbuf skeleton identical to round 11; compute gated on
// ((t0>>6)&1)==wk (wave-uniform). kf/vf read once per on-tile, reused over
// 4 subtiles -> LDS frag reads per MFMA 0.5 -> 0.25. No-max softmax is fully
// associative -> partner waves (same wq) reduce O/l once at end via LDS.
// ---------------------------------------------------------------------------
__global__ __launch_bounds__(256) void flash_attn_mfma(
    const u16* __restrict__ qg, const u16* __restrict__ kg,
    const u16* __restrict__ vtg, const float* __restrict__ biasrel,
    u16* __restrict__ attn_out) {
  __shared__ __align__(16) u16 sbuf[4 * 64 * 72];   // Ks dbuf | Vt dbuf (36 KB)
  u16 (*Ks)[64][72] = (u16(*)[64][72])sbuf;
  u16 (*Vt)[64][72] = (u16(*)[64][72])(sbuf + 2 * 64 * 72);

  const int tid = threadIdx.x;
  const int w = tid >> 6, l = tid & 63;
  const int lr = l & 15, lg = l >> 4;
  const int wq = w >> 1, wk = w & 1;

  int bid = blockIdx.x;
  int xcd = bid & 7, idx = bid >> 3;
  int bh = (xcd << 2) + (idx >> 4);
  int bx = idx & 15;
  int h = bh & 7, b = bh >> 3;
  int q0 = bx << 7;

  const u16* qp = qg + (size_t)bh * (SLEN * HDIM);
  const u16* kp = kg + (size_t)bh * (SLEN * HDIM);
  const u16* vp = vtg + (size_t)bh * (HDIM * SLEN);

  const float bias_pos = biasrel[h * RTAB + 2 * (SLEN - 1)];
  const float bias_neg = biasrel[h * RTAB];

  // Q B-frags: 4 subtiles, rows q0 + wq*64 + sub*16 + lr
  f16x8 aq[4][2];
#pragma unroll
  for (int sub = 0; sub < 4; ++sub) {
    const u16* qrow = qp + (size_t)(q0 + (wq << 6) + (sub << 4) + lr) * HDIM + (lg << 3);
    aq[sub][0] = *(const f16x8*)(qrow);
    aq[sub][1] = *(const f16x8*)(qrow + 32);
  }

  // bias index = (t0+ct*16+lg*4+r) - (q0+wq*64+sub*16+lr) + 2047
  const float* bb = biasrel + h * RTAB + (SLEN - 1) + (lg << 2) - lr - q0 - (wq << 6);

  f32x4 acc[4][4] = {};
  float l_run[4] = {0.f, 0.f, 0.f, 0.f};

  // prologue: tile 0 -> buf0; tile 1 -> regs
  u16x8 kreg[2], vreg[2];
#pragma unroll
  for (int e = 0; e < 2; ++e) {
    int c = tid + (e << 8);
    int row = c >> 3, c8 = (c & 7) << 3;
    kreg[e] = *(const u16x8*)(kp + (size_t)row * HDIM + c8);
    vreg[e] = *(const u16x8*)(vp + (size_t)row * SLEN + c8);
  }
#pragma unroll
  for (int e = 0; e < 2; ++e) {
    int c = tid + (e << 8);
    int row = c >> 3, c8 = (c & 7) << 3;
    *(u16x8*)&Ks[0][row][c8] = kreg[e];
    *(u16x8*)&Vt[0][row][c8] = vreg[e];
  }
#pragma unroll
  for (int e = 0; e < 2; ++e) {
    int c = tid + (e << 8);
    int row = c >> 3, c8 = (c & 7) << 3;
    kreg[e] = *(const u16x8*)(kp + (size_t)(64 + row) * HDIM + c8);
    vreg[e] = *(const u16x8*)(vp + (size_t)row * SLEN + 64 + c8);
  }
  __syncthreads();

  int cur = 0;
  for (int t0 = 0; t0 < SLEN; t0 += 64) {
    // stage tile t+1 into buf[cur^1]; issue loads for tile t+2
    if (t0 + 64 < SLEN) {
#pragma unroll
      for (int e = 0; e < 2; ++e) {
        int c = tid + (e << 8);
        int row = c >> 3, c8 = (c & 7) << 3;
        *(u16x8*)&Ks[cur ^ 1][row][c8] = kreg[e];
        *(u16x8*)&Vt[cur ^ 1][row][c8] = vreg[e];
      }
      if (t0 + 128 < SLEN) {
#pragma unroll
        for (int e = 0; e < 2; ++e) {
          int c = tid + (e << 8);
          int row = c >> 3, c8 = (c & 7) << 3;
          kreg[e] = *(const u16x8*)(kp + (size_t)(t0 + 128 + row) * HDIM + c8);
          vreg[e] = *(const u16x8*)(vp + (size_t)row * SLEN + t0 + 128 + c8);
        }
      }
    }

    if (((t0 >> 6) & 1) == wk) {     // wave-uniform: this wave's kv parity
      int dtq = t0 - q0;
      const int far = (dtq >= 256 || dtq <= -192);
      const float cfar = (dtq > 0) ? bias_pos : bias_neg;

      // K/V frags once per on-tile, reused across 4 subtiles
      f16x8 kf[4][2];
#pragma unroll
      for (int ct = 0; ct < 4; ++ct) {
        kf[ct][0] = *(const f16x8*)&Ks[cur][(ct << 4) + lr][lg << 3];
        kf[ct][1] = *(const f16x8*)&Ks[cur][(ct << 4) + lr][32 + (lg << 3)];
      }
      f16x8 vf[2][4];
#pragma unroll
      for (int kb = 0; kb < 2; ++kb)
#pragma unroll
        for (int dt = 0; dt < 4; ++dt)
          vf[kb][dt] = *(const f16x8*)&Vt[cur][(dt << 4) + lr][(kb << 5) + (lg << 3)];

#pragma unroll
      for (int sub = 0; sub < 4; ++sub) {
        f32x4 sc[4];
        if (far) {
          f32x4 cv = {cfar, cfar, cfar, cfar};
#pragma unroll
          for (int ct = 0; ct < 4; ++ct) sc[ct] = cv;
        } else {
#pragma unroll
          for (int ct = 0; ct < 4; ++ct)
#pragma unroll
            for (int r = 0; r < 4; ++r)
              sc[ct][r] = bb[t0 + (ct << 4) + r - (sub << 4)];
        }

        __builtin_amdgcn_s_setprio(1);
#pragma unroll
        for (int ct = 0; ct < 4; ++ct) {
          sc[ct] = __builtin_amdgcn_mfma_f32_16x16x32_f16(
              kf[ct][0], aq[sub][0], sc[ct], 0, 0, 0);
          sc[ct] = __builtin_amdgcn_mfma_f32_16x16x32_f16(
              kf[ct][1], aq[sub][1], sc[ct], 0, 0, 0);
        }
        __builtin_amdgcn_s_setprio(0);

        float rs = 0.f;
#pragma unroll
        for (int ct = 0; ct < 4; ++ct)
#pragma unroll
          for (int r = 0; r < 4; ++r) {
            float pe = __builtin_amdgcn_exp2f(sc[ct][r]);
            sc[ct][r] = pe;
            rs += pe;
          }
        l_run[sub] += rs;

        __builtin_amdgcn_s_setprio(1);
#pragma unroll
        for (int kb = 0; kb < 2; ++kb) {
          u32 a0 = __builtin_bit_cast(u32,
              __builtin_amdgcn_cvt_pkrtz(sc[2 * kb][0], sc[2 * kb][1]));
          u32 a1 = __builtin_bit_cast(u32,
              __builtin_amdgcn_cvt_pkrtz(sc[2 * kb][2], sc[2 * kb][3]));
          u32 a2 = __builtin_bit_cast(u32,
              __builtin_amdgcn_cvt_pkrtz(sc[2 * kb + 1][0], sc[2 * kb + 1][1]));
          u32 a3 = __builtin_bit_cast(u32,
              __builtin_amdgcn_cvt_pkrtz(sc[2 * kb + 1][2], sc[2 * kb + 1][3]));
          u32x4 pk = {a0, a1, a2, a3};
          f16x8 pa = __builtin_bit_cast(f16x8, pk);
#pragma unroll
          for (int dt = 0; dt < 4; ++dt)
            acc[sub][dt] = __builtin_amdgcn_mfma_f32_16x16x32_f16(
                pa, vf[kb][dt], acc[sub][dt], 0, 0, 0);
        }
        __builtin_amdgcn_s_setprio(0);
      }
    }

    __syncthreads();
    cur ^= 1;
  }

  // ---- cross-wave (wk) reduction, then epilogue by wk==0 waves ----
  float lt[4];
#pragma unroll
  for (int sub = 0; sub < 4; ++sub) {
    float t = l_run[sub];
    t += __shfl_xor(t, 16, 64);
    t += __shfl_xor(t, 32, 64);
    lt[sub] = t;
  }

  float* red = (float*)sbuf;                 // [2wq][4sub][4dt][64lane] f32x4 = 32 KB
  float* redl = (float*)sbuf + 8192;         // [2wq][4sub][16lr] = 512 B

  if (wk == 1) {
#pragma unroll
    for (int sub = 0; sub < 4; ++sub)
#pragma unroll
      for (int dt = 0; dt < 4; ++dt)
        *(f32x4*)&red[(((((wq << 2) + sub) << 2) + dt) << 8) + (l << 2)] = acc[sub][dt];
    if (lg == 0)
#pragma unroll
      for (int sub = 0; sub < 4; ++sub)
        redl[(((wq << 2) + sub) << 4) + lr] = lt[sub];
  }
  __syncthreads();
  if (wk == 0) {
#pragma unroll
    for (int sub = 0; sub < 4; ++sub) {
#pragma unroll
      for (int dt = 0; dt < 4; ++dt)
        acc[sub][dt] += *(const f32x4*)
            &red[(((((wq << 2) + sub) << 2) + dt) << 8) + (l << 2)];
      lt[sub] += redl[(((wq << 2) + sub) << 4) + lr];
    }
#pragma unroll
    for (int sub = 0; sub < 4; ++sub) {
      float linv[4];
#pragma unroll
      for (int r = 0; r < 4; ++r) linv[r] = 1.f / __shfl(lt[sub], (lg << 2) + r, 16);
      u16* op = attn_out +
                ((size_t)(b * SLEN) + q0 + (wq << 6) + (sub << 4)) * HIDDEN + (h << 6);
#pragma unroll
      for (int r = 0; r < 4; ++r)
#pragma unroll
        for (int dt = 0; dt < 4; ++dt) {
          f16 hv = (f16)(acc[sub][dt][r] * linv[r]);
          op[(size_t)((lg << 2) + r) * HIDDEN + (dt << 4) + lr] = *(u16*)&hv;
        }
    }
  }
}

// ---------------------------------------------------------------------------
extern "C" void kernel_launch(void* const* d_in, const int* in_sizes, int n_in,
                              void* d_out, int out_size, void* d_ws, size_t ws_size,
                              hipStream_t stream) {
  const float* x          = (const float*)d_in[0];
  const float* Wq         = (const float*)d_in[1];
  const float* Wk         = (const float*)d_in[2];
  const float* Wv         = (const float*)d_in[3];
  const float* Wo         = (const float*)d_in[4];
  const float* bias_table = (const float*)d_in[5];
  float* out = (float*)d_out;

  u16* xh   = (u16*)d_ws;                           // 8 MB f16 x
  u16* wt   = xh + (size_t)NROWS * HIDDEN;          // 2 MB (4 weights)
  u16* qkv  = wt + (size_t)4 * HIDDEN * HIDDEN;     // 24 MB
  u16* attno_h = qkv + (size_t)3 * NROWS * HIDDEN;  // 8 MB
  float* biasrel = (float*)(attno_h + (size_t)NROWS * HIDDEN);

  u16* qb = qkv;
  u16* kb = qkv + (size_t)NROWS * HIDDEN;
  u16* vb = qkv + (size_t)2 * NROWS * HIDDEN;   // [B,H,D,S] sigma-permuted

  bias_precompute<<<(NHEADS * RTAB + 255) / 256, 256, 0, stream>>>(bias_table, biasrel);
  conv_x<<<NROWS * HIDDEN / 8 / 256, 256, 0, stream>>>(x, xh);
  conv_w<<<dim3(HIDDEN * HIDDEN / 8 / 256, 4), 256, 0, stream>>>(Wq, Wk, Wv, Wo, wt);

  u16* wtq = wt;
  u16* wtk = wt + (size_t)HIDDEN * HIDDEN;
  u16* wtv = wt + (size_t)2 * HIDDEN * HIDDEN;
  u16* wto = wt + (size_t)3 * HIDDEN * HIDDEN;

  gemm_mfma<<<dim3(NROWS / 128, HIDDEN / 128, 3), 256, 0, stream>>>(
      xh, wtq, wtk, wtv, qkv, 1);

  flash_attn_mfma<<<SLEN / 128 * BATCH * NHEADS, 256, 0, stream>>>(
      qb, kb, vb, biasrel, attno_h);

  gemm_mfma<<<dim3(NROWS / 128, HIDDEN / 128, 1), 256, 0, stream>>>(
      attno_h, wto, wto, wto, out, 0);
}

// Round 15
// 110.878 us; speedup vs baseline: 1.6486x; 1.6486x over previous
//
#include <hip/hip_runtime.h>
#include <hip/hip_bf16.h>
#include <math.h>

#define HIDDEN 512
#define NHEADS 8
#define HDIM 64
#define SLEN 2048
#define BATCH 4
#define NROWS (BATCH*SLEN)   /* 8192 */
#define RTAB (2*SLEN-1)      /* 4095 */
#define LOG2E 1.44269504088896340736f
#define SCALE_L2E (0.125f * LOG2E)

typedef _Float16 f16;
typedef f16 f16x8 __attribute__((ext_vector_type(8)));
typedef float f32x4 __attribute__((ext_vector_type(4)));
typedef unsigned short u16;
typedef unsigned int u32;
typedef u16 u16x4 __attribute__((ext_vector_type(4)));
typedef u16 u16x8 __attribute__((ext_vector_type(8)));
typedef u32 u32x4 __attribute__((ext_vector_type(4)));

// ---------------------------------------------------------------------------
// Kernel 1: relative-position bias biasrel[h][t-s+2047], pre-scaled by log2e.
// ---------------------------------------------------------------------------
__global__ __launch_bounds__(256) void bias_precompute(
    const float* __restrict__ bias_table, float* __restrict__ biasrel) {
  int i = blockIdx.x * 256 + threadIdx.x;
  if (i >= NHEADS * RTAB) return;
  int h = i / RTAB;
  int idx = i - h * RTAB;
  int rel = idx - (SLEN - 1);
  int ret = rel > 0 ? 16 : 0;
  int a = rel < 0 ? -rel : rel;
  int bidx;
  if (a < 8) {
    bidx = a;
  } else {
    float val = logf((float)a * 0.125f) / logf(16.0f) * 8.0f;
    bidx = 8 + (int)val;
    if (bidx > 15) bidx = 15;
  }
  biasrel[i] = bias_table[(ret + bidx) * NHEADS + h] * LOG2E;
}

// ---------------------------------------------------------------------------
// Kernel 2a: x f32 -> f16
// ---------------------------------------------------------------------------
__global__ __launch_bounds__(256) void conv_x(
    const float* __restrict__ x, u16* __restrict__ xh) {
  int i = blockIdx.x * 256 + threadIdx.x;
  const float4* p = (const float4*)(x + (size_t)i * 8);
  float4 a = p[0], b = p[1];
  u16x8 o;
  f16 t0 = (f16)a.x; o[0] = *(u16*)&t0;
  f16 t1 = (f16)a.y; o[1] = *(u16*)&t1;
  f16 t2 = (f16)a.z; o[2] = *(u16*)&t2;
  f16 t3 = (f16)a.w; o[3] = *(u16*)&t3;
  f16 t4 = (f16)b.x; o[4] = *(u16*)&t4;
  f16 t5 = (f16)b.y; o[5] = *(u16*)&t5;
  f16 t6 = (f16)b.z; o[6] = *(u16*)&t6;
  f16 t7 = (f16)b.w; o[7] = *(u16*)&t7;
  *(u16x8*)(xh + (size_t)i * 8) = o;
}

// ---------------------------------------------------------------------------
// Kernel 2b: weights f32 [k][n] -> f16 transposed [n][k].
// ---------------------------------------------------------------------------
__global__ __launch_bounds__(256) void conv_w(
    const float* __restrict__ Wq, const float* __restrict__ Wk,
    const float* __restrict__ Wv, const float* __restrict__ Wo,
    u16* __restrict__ Wt) {
  const float* W = blockIdx.y == 0 ? Wq : blockIdx.y == 1 ? Wk
                 : blockIdx.y == 2 ? Wv : Wo;
  u16* dst = Wt + (size_t)blockIdx.y * HIDDEN * HIDDEN;
  int t = blockIdx.x * 256 + threadIdx.x;
  int k = t >> 6, n0 = (t & 63) << 3;
  const float4* p = (const float4*)(W + (size_t)k * HIDDEN + n0);
  float4 a = p[0], b = p[1];
  float vals[8] = {a.x, a.y, a.z, a.w, b.x, b.y, b.z, b.w};
#pragma unroll
  for (int j = 0; j < 8; ++j) {
    f16 hv = (f16)vals[j];
    dst[(size_t)(n0 + j) * HIDDEN + k] = *(u16*)&hv;
  }
}

// ---------------------------------------------------------------------------
// Kernel 3: f16 MFMA GEMM (round-11 known-good). mode 0: f32 out (Wo).
// mode 1: z=0 (Q) -> f16 [B,H,S,D] scaled by 0.125*log2e; z=1 (K) same unscaled;
//         z=2 (V) -> f16 [B,H,D,S] sigma-permuted via LDS-transpose epilogue.
// ---------------------------------------------------------------------------
__global__ __launch_bounds__(256) void gemm_mfma(
    const u16* __restrict__ A, const u16* __restrict__ Wt0,
    const u16* __restrict__ Wt1, const u16* __restrict__ Wt2,
    void* __restrict__ O, int mode) {
  __shared__ u16 sm[2 * 128 * 72];
  u16 (*As)[72] = (u16(*)[72])sm;
  u16 (*Bs)[72] = (u16(*)[72])(sm + 128 * 72);
  const u16* Wt = blockIdx.z == 0 ? Wt0 : blockIdx.z == 1 ? Wt1 : Wt2;
  const int tid = threadIdx.x;
  const int w = tid >> 6, l = tid & 63;
  const int lr = l & 15, lg = l >> 4;
  const int wr = w >> 1, wc = w & 1;
  const int m0 = blockIdx.x << 7, n0 = blockIdx.y << 7;
  const int vtmode = (mode == 1) && (blockIdx.z == 2);

  f32x4 acc[4][4] = {};

  u16x8 areg[4], breg[4];
#pragma unroll
  for (int e = 0; e < 4; ++e) {
    int c = (e << 8) + tid;
    int row = c >> 3, g = c & 7;
    areg[e] = *(const u16x8*)(A + (size_t)(m0 + row) * HIDDEN + (g << 3));
    breg[e] = *(const u16x8*)(Wt + (size_t)(n0 + row) * HIDDEN + (g << 3));
  }

  for (int k0 = 0; k0 < HIDDEN; k0 += 64) {
    __syncthreads();
#pragma unroll
    for (int e = 0; e < 4; ++e) {
      int c = (e << 8) + tid;
      int row = c >> 3, g = c & 7;
      *(u16x8*)&As[row][g << 3] = areg[e];
      *(u16x8*)&Bs[row][g << 3] = breg[e];
    }
    __syncthreads();
    if (k0 + 64 < HIDDEN) {
#pragma unroll
      for (int e = 0; e < 4; ++e) {
        int c = (e << 8) + tid;
        int row = c >> 3, g = c & 7;
        areg[e] = *(const u16x8*)(A + (size_t)(m0 + row) * HIDDEN + k0 + 64 + (g << 3));
        breg[e] = *(const u16x8*)(Wt + (size_t)(n0 + row) * HIDDEN + k0 + 64 + (g << 3));
      }
    }
#pragma unroll
    for (int kk = 0; kk < 64; kk += 32) {
      f16x8 af[4], bf[4];
#pragma unroll
      for (int mt = 0; mt < 4; ++mt)
        af[mt] = *(const f16x8*)&As[(wr << 6) + (mt << 4) + lr][kk + (lg << 3)];
#pragma unroll
      for (int nt = 0; nt < 4; ++nt)
        bf[nt] = *(const f16x8*)&Bs[(wc << 6) + (nt << 4) + lr][kk + (lg << 3)];
      if (!vtmode) {
#pragma unroll
        for (int mt = 0; mt < 4; ++mt)
#pragma unroll
          for (int nt = 0; nt < 4; ++nt)
            acc[mt][nt] = __builtin_amdgcn_mfma_f32_16x16x32_f16(
                af[mt], bf[nt], acc[mt][nt], 0, 0, 0);
      } else {
#pragma unroll
        for (int i = 0; i < 4; ++i)
#pragma unroll
          for (int j = 0; j < 4; ++j)
            acc[i][j] = __builtin_amdgcn_mfma_f32_16x16x32_f16(
                bf[i], af[j], acc[i][j], 0, 0, 0);
      }
    }
  }

  if (mode == 0) {
    float* Of = (float*)O;
#pragma unroll
    for (int mt = 0; mt < 4; ++mt)
#pragma unroll
      for (int nt = 0; nt < 4; ++nt)
#pragma unroll
        for (int r = 0; r < 4; ++r) {
          int m = m0 + (wr << 6) + (mt << 4) + (lg << 2) + r;
          int n = n0 + (wc << 6) + (nt << 4) + lr;
          Of[(size_t)m * HIDDEN + n] = acc[mt][nt][r];
        }
  } else if (!vtmode) {
    u16* O16 = (u16*)O + (size_t)blockIdx.z * NROWS * HIDDEN;
    const float osc = (blockIdx.z == 0) ? SCALE_L2E : 1.0f;
#pragma unroll
    for (int mt = 0; mt < 4; ++mt)
#pragma unroll
      for (int nt = 0; nt < 4; ++nt)
#pragma unroll
        for (int r = 0; r < 4; ++r) {
          int m = m0 + (wr << 6) + (mt << 4) + (lg << 2) + r;
          int n = n0 + (wc << 6) + (nt << 4) + lr;
          int b = m >> 11, s = m & (SLEN - 1);
          int h = n >> 6, d = n & 63;
          f16 hv = (f16)(acc[mt][nt][r] * osc);
          O16[(((size_t)b * NHEADS + h) * SLEN + s) * HDIM + d] = *(u16*)&hv;
        }
  } else {
    __syncthreads();
    u16* tt = sm;                           // tile[128][136]: [n_loc][m_loc]
#pragma unroll
    for (int i = 0; i < 4; ++i)
#pragma unroll
      for (int j = 0; j < 4; ++j)
#pragma unroll
        for (int r = 0; r < 4; ++r) {
          int nl = (wc << 6) + (i << 4) + (lg << 2) + r;
          int ml = (wr << 6) + (j << 4) + lr;
          f16 hv = (f16)acc[i][j][r];
          tt[nl * 136 + ml] = *(u16*)&hv;
        }
    __syncthreads();
    u16* O16 = (u16*)O + (size_t)2 * NROWS * HIDDEN;
    int nl = tid >> 1, half = tid & 1;
    int n = n0 + nl;
    int h = n >> 6, d = n & 63;
    int b = m0 >> 11, s_base = m0 & (SLEN - 1);
    u16* orow = O16 + (((size_t)b * NHEADS + h) * HDIM + d) * SLEN + s_base;
    const u16* trow = tt + nl * 136;
#pragma unroll
    for (int c = 0; c < 8; ++c) {
      int v_off = (half << 6) + (c << 3);
      int c0 = (v_off & ~31) | (((v_off >> 3) & 3) << 2);
      u16x4 lo = *(const u16x4*)(trow + c0);
      u16x4 hi = *(const u16x4*)(trow + c0 + 16);
      u16x8 st;
#pragma unroll
      for (int j = 0; j < 4; ++j) { st[j] = lo[j]; st[j + 4] = hi[j]; }
      *(u16x8*)(orow + v_off) = st;
    }
  }
}

// ---------------------------------------------------------------------------
// Kernel 4: flash attention, q x kv wave split WITHOUT gating.
// Wave (wq=w>>1, wkb=w&1): wq owns 64 q-rows (4 subtiles); wkb owns the kv
// half (kb) of EVERY tile -> all SIMDs busy every tile (fixes round-13).
// PV kb=wkb needs only ct in {2wkb, 2wkb+1} -> QK computes just those 2 ct.
// Per wave-tile: 16 QK + 16 PV MFMAs (same as round 11), frag reads 16->8.
// acc/l hold kv-half partials (no-max softmax = fully associative); one
// LDS reduction at end (round-13-proven code). Staging/dbuf = round 11.
// ---------------------------------------------------------------------------
__global__ __launch_bounds__(256) void flash_attn_mfma(
    const u16* __restrict__ qg, const u16* __restrict__ kg,
    const u16* __restrict__ vtg, const float* __restrict__ biasrel,
    u16* __restrict__ attn_out) {
  __shared__ __align__(16) u16 sbuf[4 * 64 * 72];   // Ks dbuf | Vt dbuf (36 KB)
  u16 (*Ks)[64][72] = (u16(*)[64][72])sbuf;
  u16 (*Vt)[64][72] = (u16(*)[64][72])(sbuf + 2 * 64 * 72);

  const int tid = threadIdx.x;
  const int w = tid >> 6, l = tid & 63;
  const int lr = l & 15, lg = l >> 4;
  const int wq = w >> 1, wkb = w & 1;

  int bid = blockIdx.x;
  int xcd = bid & 7, idx = bid >> 3;
  int bh = (xcd << 2) + (idx >> 4);
  int bx = idx & 15;
  int h = bh & 7, b = bh >> 3;
  int q0 = bx << 7;

  const u16* qp = qg + (size_t)bh * (SLEN * HDIM);
  const u16* kp = kg + (size_t)bh * (SLEN * HDIM);
  const u16* vp = vtg + (size_t)bh * (HDIM * SLEN);

  const float bias_pos = biasrel[h * RTAB + 2 * (SLEN - 1)];
  const float bias_neg = biasrel[h * RTAB];

  // Q B-frags: 4 subtiles of this wave's 64-row q-half
  f16x8 aq[4][2];
#pragma unroll
  for (int sub = 0; sub < 4; ++sub) {
    const u16* qrow = qp + (size_t)(q0 + (wq << 6) + (sub << 4) + lr) * HDIM + (lg << 3);
    aq[sub][0] = *(const f16x8*)(qrow);
    aq[sub][1] = *(const f16x8*)(qrow + 32);
  }

  // bias index = (t0+ct*16+lg*4+r) - (q0+wq*64+sub*16+lr) + 2047
  const float* bb = biasrel + h * RTAB + (SLEN - 1) + (lg << 2) - lr - q0 - (wq << 6);

  f32x4 acc[4][4] = {};                 // [sub][dt], kv-half partial
  float l_run[4] = {0.f, 0.f, 0.f, 0.f};

  // prologue: tile 0 -> buf0; tile 1 -> regs
  u16x8 kreg[2], vreg[2];
#pragma unroll
  for (int e = 0; e < 2; ++e) {
    int c = tid + (e << 8);
    int row = c >> 3, c8 = (c & 7) << 3;
    kreg[e] = *(const u16x8*)(kp + (size_t)row * HDIM + c8);
    vreg[e] = *(const u16x8*)(vp + (size_t)row * SLEN + c8);
  }
#pragma unroll
  for (int e = 0; e < 2; ++e) {
    int c = tid + (e << 8);
    int row = c >> 3, c8 = (c & 7) << 3;
    *(u16x8*)&Ks[0][row][c8] = kreg[e];
    *(u16x8*)&Vt[0][row][c8] = vreg[e];
  }
#pragma unroll
  for (int e = 0; e < 2; ++e) {
    int c = tid + (e << 8);
    int row = c >> 3, c8 = (c & 7) << 3;
    kreg[e] = *(const u16x8*)(kp + (size_t)(64 + row) * HDIM + c8);
    vreg[e] = *(const u16x8*)(vp + (size_t)row * SLEN + 64 + c8);
  }
  __syncthreads();

  int cur = 0;
  for (int t0 = 0; t0 < SLEN; t0 += 64) {
    // stage tile t+1 into buf[cur^1]; issue loads for tile t+2
    if (t0 + 64 < SLEN) {
#pragma unroll
      for (int e = 0; e < 2; ++e) {
        int c = tid + (e << 8);
        int row = c >> 3, c8 = (c & 7) << 3;
        *(u16x8*)&Ks[cur ^ 1][row][c8] = kreg[e];
        *(u16x8*)&Vt[cur ^ 1][row][c8] = vreg[e];
      }
      if (t0 + 128 < SLEN) {
#pragma unroll
        for (int e = 0; e < 2; ++e) {
          int c = tid + (e << 8);
          int row = c >> 3, c8 = (c & 7) << 3;
          kreg[e] = *(const u16x8*)(kp + (size_t)(t0 + 128 + row) * HDIM + c8);
          vreg[e] = *(const u16x8*)(vp + (size_t)row * SLEN + t0 + 128 + c8);
        }
      }
    }

    int dtq = t0 - q0;
    const int far = (dtq >= 256 || dtq <= -192);
    const float cfar = (dtq > 0) ? bias_pos : bias_neg;

    // this wave's K frags (2 ct) and V frags (its kb), reused over 4 subtiles
    f16x8 kf[2][2];
#pragma unroll
    for (int cc = 0; cc < 2; ++cc) {
      int ct = (wkb << 1) + cc;
      kf[cc][0] = *(const f16x8*)&Ks[cur][(ct << 4) + lr][lg << 3];
      kf[cc][1] = *(const f16x8*)&Ks[cur][(ct << 4) + lr][32 + (lg << 3)];
    }
    f16x8 vf[4];
#pragma unroll
    for (int dt = 0; dt < 4; ++dt)
      vf[dt] = *(const f16x8*)&Vt[cur][(dt << 4) + lr][(wkb << 5) + (lg << 3)];

#pragma unroll
    for (int sub = 0; sub < 4; ++sub) {
      f32x4 sc[2];
      if (far) {
        f32x4 cv = {cfar, cfar, cfar, cfar};
        sc[0] = cv; sc[1] = cv;
      } else {
#pragma unroll
        for (int cc = 0; cc < 2; ++cc)
#pragma unroll
          for (int r = 0; r < 4; ++r)
            sc[cc][r] = bb[t0 + (((wkb << 1) + cc) << 4) + r - (sub << 4)];
      }

      __builtin_amdgcn_s_setprio(1);
#pragma unroll
      for (int cc = 0; cc < 2; ++cc) {
        sc[cc] = __builtin_amdgcn_mfma_f32_16x16x32_f16(
            kf[cc][0], aq[sub][0], sc[cc], 0, 0, 0);
        sc[cc] = __builtin_amdgcn_mfma_f32_16x16x32_f16(
            kf[cc][1], aq[sub][1], sc[cc], 0, 0, 0);
      }
      __builtin_amdgcn_s_setprio(0);

      float rs = 0.f;
#pragma unroll
      for (int cc = 0; cc < 2; ++cc)
#pragma unroll
        for (int r = 0; r < 4; ++r) {
          float pe = __builtin_amdgcn_exp2f(sc[cc][r]);
          sc[cc][r] = pe;
          rs += pe;
        }
      l_run[sub] += rs;

      u32 a0 = __builtin_bit_cast(u32,
          __builtin_amdgcn_cvt_pkrtz(sc[0][0], sc[0][1]));
      u32 a1 = __builtin_bit_cast(u32,
          __builtin_amdgcn_cvt_pkrtz(sc[0][2], sc[0][3]));
      u32 a2 = __builtin_bit_cast(u32,
          __builtin_amdgcn_cvt_pkrtz(sc[1][0], sc[1][1]));
      u32 a3 = __builtin_bit_cast(u32,
          __builtin_amdgcn_cvt_pkrtz(sc[1][2], sc[1][3]));
      u32x4 pk = {a0, a1, a2, a3};
      f16x8 pa = __builtin_bit_cast(f16x8, pk);

      __builtin_amdgcn_s_setprio(1);
#pragma unroll
      for (int dt = 0; dt < 4; ++dt)
        acc[sub][dt] = __builtin_amdgcn_mfma_f32_16x16x32_f16(
            pa, vf[dt], acc[sub][dt], 0, 0, 0);
      __builtin_amdgcn_s_setprio(0);
    }

    __syncthreads();
    cur ^= 1;
  }

  // ---- cross-wave (wkb) reduction, then epilogue by wkb==0 waves ----
  float lt[4];
#pragma unroll
  for (int sub = 0; sub < 4; ++sub) {
    float t = l_run[sub];
    t += __shfl_xor(t, 16, 64);
    t += __shfl_xor(t, 32, 64);
    lt[sub] = t;
  }

  float* red = (float*)sbuf;                 // [2wq][4sub][4dt][64lane] f32x4 = 32 KB
  float* redl = (float*)sbuf + 8192;         // [2wq][4sub][16lr]

  if (wkb == 1) {
#pragma unroll
    for (int sub = 0; sub < 4; ++sub)
#pragma unroll
      for (int dt = 0; dt < 4; ++dt)
        *(f32x4*)&red[(((((wq << 2) + sub) << 2) + dt) << 8) + (l << 2)] = acc[sub][dt];
    if (lg == 0)
#pragma unroll
      for (int sub = 0; sub < 4; ++sub)
        redl[(((wq << 2) + sub) << 4) + lr] = lt[sub];
  }
  __syncthreads();
  if (wkb == 0) {
#pragma unroll
    for (int sub = 0; sub < 4; ++sub) {
#pragma unroll
      for (int dt = 0; dt < 4; ++dt)
        acc[sub][dt] += *(const f32x4*)
            &red[(((((wq << 2) + sub) << 2) + dt) << 8) + (l << 2)];
      lt[sub] += redl[(((wq << 2) + sub) << 4) + lr];
    }
#pragma unroll
    for (int sub = 0; sub < 4; ++sub) {
      float linv[4];
#pragma unroll
      for (int r = 0; r < 4; ++r) linv[r] = 1.f / __shfl(lt[sub], (lg << 2) + r, 16);
      u16* op = attn_out +
                ((size_t)(b * SLEN) + q0 + (wq << 6) + (sub << 4)) * HIDDEN + (h << 6);
#pragma unroll
      for (int r = 0; r < 4; ++r)
#pragma unroll
        for (int dt = 0; dt < 4; ++dt) {
          f16 hv = (f16)(acc[sub][dt][r] * linv[r]);
          op[(size_t)((lg << 2) + r) * HIDDEN + (dt << 4) + lr] = *(u16*)&hv;
        }
    }
  }
}

// ---------------------------------------------------------------------------
extern "C" void kernel_launch(void* const* d_in, const int* in_sizes, int n_in,
                              void* d_out, int out_size, void* d_ws, size_t ws_size,
                              hipStream_t stream) {
  const float* x          = (const float*)d_in[0];
  const float* Wq         = (const float*)d_in[1];
  const float* Wk         = (const float*)d_in[2];
  const float* Wv         = (const float*)d_in[3];
  const float* Wo         = (const float*)d_in[4];
  const float* bias_table = (const float*)d_in[5];
  float* out = (float*)d_out;

  u16* xh   = (u16*)d_ws;                           // 8 MB f16 x
  u16* wt   = xh + (size_t)NROWS * HIDDEN;          // 2 MB (4 weights)
  u16* qkv  = wt + (size_t)4 * HIDDEN * HIDDEN;     // 24 MB
  u16* attno_h = qkv + (size_t)3 * NROWS * HIDDEN;  // 8 MB
  float* biasrel = (float*)(attno_h + (size_t)NROWS * HIDDEN);

  u16* qb = qkv;
  u16* kb = qkv + (size_t)NROWS * HIDDEN;
  u16* vb = qkv + (size_t)2 * NROWS * HIDDEN;   // [B,H,D,S] sigma-permuted

  bias_precompute<<<(NHEADS * RTAB + 255) / 256, 256, 0, stream>>>(bias_table, biasrel);
  conv_x<<<NROWS * HIDDEN / 8 / 256, 256, 0, stream>>>(x, xh);
  conv_w<<<dim3(HIDDEN * HIDDEN / 8 / 256, 4), 256, 0, stream>>>(Wq, Wk, Wv, Wo, wt);

  u16* wtq = wt;
  u16* wtk = wt + (size_t)HIDDEN * HIDDEN;
  u16* wtv = wt + (size_t)2 * HIDDEN * HIDDEN;
  u16* wto = wt + (size_t)3 * HIDDEN * HIDDEN;

  gemm_mfma<<<dim3(NROWS / 128, HIDDEN / 128, 3), 256, 0, stream>>>(
      xh, wtq, wtk, wtv, qkv, 1);

  flash_attn_mfma<<<SLEN / 128 * BATCH * NHEADS, 256, 0, stream>>>(
      qb, kb, vb, biasrel, attno_h);

  gemm_mfma<<<dim3(NROWS / 128, HIDDEN / 128, 1), 256, 0, stream>>>(
      attno_h, wto, wto, wto, out, 0);
}

// Round 16
// 104.942 us; speedup vs baseline: 1.7418x; 1.0566x over previous
//
#include <hip/hip_runtime.h>
#include <hip/hip_bf16.h>
#include <math.h>

#define HIDDEN 512
#define NHEADS 8
#define HDIM 64
#define SLEN 2048
#define BATCH 4
#define NROWS (BATCH*SLEN)   /* 8192 */
#define RTAB (2*SLEN-1)      /* 4095 */
#define LOG2E 1.44269504088896340736f
#define SCALE_L2E (0.125f * LOG2E)

typedef _Float16 f16;
typedef f16 f16x8 __attribute__((ext_vector_type(8)));
typedef float f32x4 __attribute__((ext_vector_type(4)));
typedef unsigned short u16;
typedef unsigned int u32;
typedef u16 u16x4 __attribute__((ext_vector_type(4)));
typedef u16 u16x8 __attribute__((ext_vector_type(8)));
typedef u32 u32x4 __attribute__((ext_vector_type(4)));

// ---------------------------------------------------------------------------
// Kernel 1: relative-position bias biasrel[h][t-s+2047], pre-scaled by log2e.
// ---------------------------------------------------------------------------
__global__ __launch_bounds__(256) void bias_precompute(
    const float* __restrict__ bias_table, float* __restrict__ biasrel) {
  int i = blockIdx.x * 256 + threadIdx.x;
  if (i >= NHEADS * RTAB) return;
  int h = i / RTAB;
  int idx = i - h * RTAB;
  int rel = idx - (SLEN - 1);
  int ret = rel > 0 ? 16 : 0;
  int a = rel < 0 ? -rel : rel;
  int bidx;
  if (a < 8) {
    bidx = a;
  } else {
    float val = logf((float)a * 0.125f) / logf(16.0f) * 8.0f;
    bidx = 8 + (int)val;
    if (bidx > 15) bidx = 15;
  }
  biasrel[i] = bias_table[(ret + bidx) * NHEADS + h] * LOG2E;
}

// ---------------------------------------------------------------------------
// Kernel 2a: x f32 -> f16
// ---------------------------------------------------------------------------
__global__ __launch_bounds__(256) void conv_x(
    const float* __restrict__ x, u16* __restrict__ xh) {
  int i = blockIdx.x * 256 + threadIdx.x;
  const float4* p = (const float4*)(x + (size_t)i * 8);
  float4 a = p[0], b = p[1];
  u16x8 o;
  f16 t0 = (f16)a.x; o[0] = *(u16*)&t0;
  f16 t1 = (f16)a.y; o[1] = *(u16*)&t1;
  f16 t2 = (f16)a.z; o[2] = *(u16*)&t2;
  f16 t3 = (f16)a.w; o[3] = *(u16*)&t3;
  f16 t4 = (f16)b.x; o[4] = *(u16*)&t4;
  f16 t5 = (f16)b.y; o[5] = *(u16*)&t5;
  f16 t6 = (f16)b.z; o[6] = *(u16*)&t6;
  f16 t7 = (f16)b.w; o[7] = *(u16*)&t7;
  *(u16x8*)(xh + (size_t)i * 8) = o;
}

// ---------------------------------------------------------------------------
// Kernel 2b: weights f32 [k][n] -> f16 transposed [n][k].
// ---------------------------------------------------------------------------
__global__ __launch_bounds__(256) void conv_w(
    const float* __restrict__ Wq, const float* __restrict__ Wk,
    const float* __restrict__ Wv, const float* __restrict__ Wo,
    u16* __restrict__ Wt) {
  const float* W = blockIdx.y == 0 ? Wq : blockIdx.y == 1 ? Wk
                 : blockIdx.y == 2 ? Wv : Wo;
  u16* dst = Wt + (size_t)blockIdx.y * HIDDEN * HIDDEN;
  int t = blockIdx.x * 256 + threadIdx.x;
  int k = t >> 6, n0 = (t & 63) << 3;
  const float4* p = (const float4*)(W + (size_t)k * HIDDEN + n0);
  float4 a = p[0], b = p[1];
  float vals[8] = {a.x, a.y, a.z, a.w, b.x, b.y, b.z, b.w};
#pragma unroll
  for (int j = 0; j < 8; ++j) {
    f16 hv = (f16)vals[j];
    dst[(size_t)(n0 + j) * HIDDEN + k] = *(u16*)&hv;
  }
}

// ---------------------------------------------------------------------------
// Kernel 3: f16 MFMA GEMM (round-11 known-good). mode 0: f32 out (Wo).
// mode 1: z=0 (Q) -> f16 [B,H,S,D] scaled by 0.125*log2e; z=1 (K) unscaled;
//         z=2 (V) -> f16 [B,H,D,S] sigma-permuted via LDS-transpose epilogue.
// ---------------------------------------------------------------------------
__global__ __launch_bounds__(256) void gemm_mfma(
    const u16* __restrict__ A, const u16* __restrict__ Wt0,
    const u16* __restrict__ Wt1, const u16* __restrict__ Wt2,
    void* __restrict__ O, int mode) {
  __shared__ u16 sm[2 * 128 * 72];
  u16 (*As)[72] = (u16(*)[72])sm;
  u16 (*Bs)[72] = (u16(*)[72])(sm + 128 * 72);
  const u16* Wt = blockIdx.z == 0 ? Wt0 : blockIdx.z == 1 ? Wt1 : Wt2;
  const int tid = threadIdx.x;
  const int w = tid >> 6, l = tid & 63;
  const int lr = l & 15, lg = l >> 4;
  const int wr = w >> 1, wc = w & 1;
  const int m0 = blockIdx.x << 7, n0 = blockIdx.y << 7;
  const int vtmode = (mode == 1) && (blockIdx.z == 2);

  f32x4 acc[4][4] = {};

  u16x8 areg[4], breg[4];
#pragma unroll
  for (int e = 0; e < 4; ++e) {
    int c = (e << 8) + tid;
    int row = c >> 3, g = c & 7;
    areg[e] = *(const u16x8*)(A + (size_t)(m0 + row) * HIDDEN + (g << 3));
    breg[e] = *(const u16x8*)(Wt + (size_t)(n0 + row) * HIDDEN + (g << 3));
  }

  for (int k0 = 0; k0 < HIDDEN; k0 += 64) {
    __syncthreads();
#pragma unroll
    for (int e = 0; e < 4; ++e) {
      int c = (e << 8) + tid;
      int row = c >> 3, g = c & 7;
      *(u16x8*)&As[row][g << 3] = areg[e];
      *(u16x8*)&Bs[row][g << 3] = breg[e];
    }
    __syncthreads();
    if (k0 + 64 < HIDDEN) {
#pragma unroll
      for (int e = 0; e < 4; ++e) {
        int c = (e << 8) + tid;
        int row = c >> 3, g = c & 7;
        areg[e] = *(const u16x8*)(A + (size_t)(m0 + row) * HIDDEN + k0 + 64 + (g << 3));
        breg[e] = *(const u16x8*)(Wt + (size_t)(n0 + row) * HIDDEN + k0 + 64 + (g << 3));
      }
    }
#pragma unroll
    for (int kk = 0; kk < 64; kk += 32) {
      f16x8 af[4], bf[4];
#pragma unroll
      for (int mt = 0; mt < 4; ++mt)
        af[mt] = *(const f16x8*)&As[(wr << 6) + (mt << 4) + lr][kk + (lg << 3)];
#pragma unroll
      for (int nt = 0; nt < 4; ++nt)
        bf[nt] = *(const f16x8*)&Bs[(wc << 6) + (nt << 4) + lr][kk + (lg << 3)];
      if (!vtmode) {
#pragma unroll
        for (int mt = 0; mt < 4; ++mt)
#pragma unroll
          for (int nt = 0; nt < 4; ++nt)
            acc[mt][nt] = __builtin_amdgcn_mfma_f32_16x16x32_f16(
                af[mt], bf[nt], acc[mt][nt], 0, 0, 0);
      } else {
#pragma unroll
        for (int i = 0; i < 4; ++i)
#pragma unroll
          for (int j = 0; j < 4; ++j)
            acc[i][j] = __builtin_amdgcn_mfma_f32_16x16x32_f16(
                bf[i], af[j], acc[i][j], 0, 0, 0);
      }
    }
  }

  if (mode == 0) {
    float* Of = (float*)O;
#pragma unroll
    for (int mt = 0; mt < 4; ++mt)
#pragma unroll
      for (int nt = 0; nt < 4; ++nt)
#pragma unroll
        for (int r = 0; r < 4; ++r) {
          int m = m0 + (wr << 6) + (mt << 4) + (lg << 2) + r;
          int n = n0 + (wc << 6) + (nt << 4) + lr;
          Of[(size_t)m * HIDDEN + n] = acc[mt][nt][r];
        }
  } else if (!vtmode) {
    u16* O16 = (u16*)O + (size_t)blockIdx.z * NROWS * HIDDEN;
    const float osc = (blockIdx.z == 0) ? SCALE_L2E : 1.0f;
#pragma unroll
    for (int mt = 0; mt < 4; ++mt)
#pragma unroll
      for (int nt = 0; nt < 4; ++nt)
#pragma unroll
        for (int r = 0; r < 4; ++r) {
          int m = m0 + (wr << 6) + (mt << 4) + (lg << 2) + r;
          int n = n0 + (wc << 6) + (nt << 4) + lr;
          int b = m >> 11, s = m & (SLEN - 1);
          int h = n >> 6, d = n & 63;
          f16 hv = (f16)(acc[mt][nt][r] * osc);
          O16[(((size_t)b * NHEADS + h) * SLEN + s) * HDIM + d] = *(u16*)&hv;
        }
  } else {
    __syncthreads();
    u16* tt = sm;                           // tile[128][136]: [n_loc][m_loc]
#pragma unroll
    for (int i = 0; i < 4; ++i)
#pragma unroll
      for (int j = 0; j < 4; ++j)
#pragma unroll
        for (int r = 0; r < 4; ++r) {
          int nl = (wc << 6) + (i << 4) + (lg << 2) + r;
          int ml = (wr << 6) + (j << 4) + lr;
          f16 hv = (f16)acc[i][j][r];
          tt[nl * 136 + ml] = *(u16*)&hv;
        }
    __syncthreads();
    u16* O16 = (u16*)O + (size_t)2 * NROWS * HIDDEN;
    int nl = tid >> 1, half = tid & 1;
    int n = n0 + nl;
    int h = n >> 6, d = n & 63;
    int b = m0 >> 11, s_base = m0 & (SLEN - 1);
    u16* orow = O16 + (((size_t)b * NHEADS + h) * HDIM + d) * SLEN + s_base;
    const u16* trow = tt + nl * 136;
#pragma unroll
    for (int c = 0; c < 8; ++c) {
      int v_off = (half << 6) + (c << 3);
      int c0 = (v_off & ~31) | (((v_off >> 3) & 3) << 2);
      u16x4 lo = *(const u16x4*)(trow + c0);
      u16x4 hi = *(const u16x4*)(trow + c0 + 16);
      u16x8 st;
#pragma unroll
      for (int j = 0; j < 4; ++j) { st[j] = lo[j]; st[j + 4] = hi[j]; }
      *(u16x8*)(orow + v_off) = st;
    }
  }
}

// ---------------------------------------------------------------------------
// Kernel 4: flash attention (round-11 structure) + l-via-MFMA:
// accl[sub] = mfma(pa, ones, accl) gives l[q=lg*4+r] in accl[sub][r] at every
// lane -> no rs fadds, no shfl reductions, no epilogue redistribution.
// Single-barrier LDS dbuf, no-max softmax, bias in MFMA C, far-tile const
// bias, swapped QK^T, sigma-permuted V^T b128 frags.
// ---------------------------------------------------------------------------
__global__ __launch_bounds__(256) void flash_attn_mfma(
    const u16* __restrict__ qg, const u16* __restrict__ kg,
    const u16* __restrict__ vtg, const float* __restrict__ biasrel,
    u16* __restrict__ attn_out) {
  __shared__ u16 Ks[2][64][72];   // [buf][kv][d]
  __shared__ u16 Vt[2][64][72];   // [buf][d][kv] (sigma-permuted kv)

  const int tid = threadIdx.x;
  const int w = tid >> 6, l = tid & 63;
  const int lr = l & 15, lg = l >> 4;

  int bid = blockIdx.x;
  int xcd = bid & 7, idx = bid >> 3;
  int bh = (xcd << 2) + (idx >> 4);
  int bx = idx & 15;
  int h = bh & 7, b = bh >> 3;
  int q0 = bx << 7;

  const u16* qp = qg + (size_t)bh * (SLEN * HDIM);
  const u16* kp = kg + (size_t)bh * (SLEN * HDIM);
  const u16* vp = vtg + (size_t)bh * (HDIM * SLEN);

  const float bias_pos = biasrel[h * RTAB + 2 * (SLEN - 1)];
  const float bias_neg = biasrel[h * RTAB];

  f16x8 aq[2][2];
#pragma unroll
  for (int sub = 0; sub < 2; ++sub) {
    const u16* qrow = qp + (size_t)(q0 + (w << 5) + (sub << 4) + lr) * HDIM + (lg << 3);
    aq[sub][0] = *(const f16x8*)(qrow);
    aq[sub][1] = *(const f16x8*)(qrow + 32);
  }

  const float* bb = biasrel + h * RTAB + (SLEN - 1) + (lg << 2) - lr - q0 - (w << 5);

  f32x4 acc[2][4] = {};
  f32x4 accl[2] = {};                  // l[q=lg*4+r] accumulated via ones-MFMA
  const f16x8 ones = {(f16)1.f, (f16)1.f, (f16)1.f, (f16)1.f,
                      (f16)1.f, (f16)1.f, (f16)1.f, (f16)1.f};

  u16x8 kreg[2], vreg[2];
#pragma unroll
  for (int e = 0; e < 2; ++e) {
    int c = tid + (e << 8);
    int row = c >> 3, c8 = (c & 7) << 3;
    kreg[e] = *(const u16x8*)(kp + (size_t)row * HDIM + c8);
    vreg[e] = *(const u16x8*)(vp + (size_t)row * SLEN + c8);
  }
#pragma unroll
  for (int e = 0; e < 2; ++e) {
    int c = tid + (e << 8);
    int row = c >> 3, c8 = (c & 7) << 3;
    *(u16x8*)&Ks[0][row][c8] = kreg[e];
    *(u16x8*)&Vt[0][row][c8] = vreg[e];
  }
#pragma unroll
  for (int e = 0; e < 2; ++e) {
    int c = tid + (e << 8);
    int row = c >> 3, c8 = (c & 7) << 3;
    kreg[e] = *(const u16x8*)(kp + (size_t)(64 + row) * HDIM + c8);
    vreg[e] = *(const u16x8*)(vp + (size_t)row * SLEN + 64 + c8);
  }
  __syncthreads();

  int cur = 0;
  for (int t0 = 0; t0 < SLEN; t0 += 64) {
    if (t0 + 64 < SLEN) {
#pragma unroll
      for (int e = 0; e < 2; ++e) {
        int c = tid + (e << 8);
        int row = c >> 3, c8 = (c & 7) << 3;
        *(u16x8*)&Ks[cur ^ 1][row][c8] = kreg[e];
        *(u16x8*)&Vt[cur ^ 1][row][c8] = vreg[e];
      }
      if (t0 + 128 < SLEN) {
#pragma unroll
        for (int e = 0; e < 2; ++e) {
          int c = tid + (e << 8);
          int row = c >> 3, c8 = (c & 7) << 3;
          kreg[e] = *(const u16x8*)(kp + (size_t)(t0 + 128 + row) * HDIM + c8);
          vreg[e] = *(const u16x8*)(vp + (size_t)row * SLEN + t0 + 128 + c8);
        }
      }
    }

    int dtq = t0 - q0;
    f32x4 sc[2][4];
    if (dtq >= 256 || dtq <= -192) {
      float c = (dtq > 0) ? bias_pos : bias_neg;
      f32x4 cv = {c, c, c, c};
#pragma unroll
      for (int sub = 0; sub < 2; ++sub)
#pragma unroll
        for (int ct = 0; ct < 4; ++ct) sc[sub][ct] = cv;
    } else {
#pragma unroll
      for (int sub = 0; sub < 2; ++sub)
#pragma unroll
        for (int ct = 0; ct < 4; ++ct)
#pragma unroll
          for (int r = 0; r < 4; ++r)
            sc[sub][ct][r] = bb[t0 + (ct << 4) + r - (sub << 4)];
    }

    f16x8 kf[4][2];
#pragma unroll
    for (int ct = 0; ct < 4; ++ct) {
      kf[ct][0] = *(const f16x8*)&Ks[cur][(ct << 4) + lr][lg << 3];
      kf[ct][1] = *(const f16x8*)&Ks[cur][(ct << 4) + lr][32 + (lg << 3)];
    }

    __builtin_amdgcn_s_setprio(1);
#pragma unroll
    for (int sub = 0; sub < 2; ++sub)
#pragma unroll
      for (int ct = 0; ct < 4; ++ct) {
        sc[sub][ct] = __builtin_amdgcn_mfma_f32_16x16x32_f16(
            kf[ct][0], aq[sub][0], sc[sub][ct], 0, 0, 0);
        sc[sub][ct] = __builtin_amdgcn_mfma_f32_16x16x32_f16(
            kf[ct][1], aq[sub][1], sc[sub][ct], 0, 0, 0);
      }
    __builtin_amdgcn_s_setprio(0);

    // no-max softmax: pe = exp2(sv); no reductions (l via ones-MFMA below)
#pragma unroll
    for (int sub = 0; sub < 2; ++sub)
#pragma unroll
      for (int ct = 0; ct < 4; ++ct)
#pragma unroll
        for (int r = 0; r < 4; ++r)
          sc[sub][ct][r] = __builtin_amdgcn_exp2f(sc[sub][ct][r]);

    f16x8 vf[2][4];
#pragma unroll
    for (int kb = 0; kb < 2; ++kb)
#pragma unroll
      for (int dt = 0; dt < 4; ++dt)
        vf[kb][dt] = *(const f16x8*)&Vt[cur][(dt << 4) + lr][(kb << 5) + (lg << 3)];

    __builtin_amdgcn_s_setprio(1);
#pragma unroll
    for (int sub = 0; sub < 2; ++sub)
#pragma unroll
      for (int kb = 0; kb < 2; ++kb) {
        u32 a0 = __builtin_bit_cast(u32,
            __builtin_amdgcn_cvt_pkrtz(sc[sub][2 * kb][0], sc[sub][2 * kb][1]));
        u32 a1 = __builtin_bit_cast(u32,
            __builtin_amdgcn_cvt_pkrtz(sc[sub][2 * kb][2], sc[sub][2 * kb][3]));
        u32 a2 = __builtin_bit_cast(u32,
            __builtin_amdgcn_cvt_pkrtz(sc[sub][2 * kb + 1][0], sc[sub][2 * kb + 1][1]));
        u32 a3 = __builtin_bit_cast(u32,
            __builtin_amdgcn_cvt_pkrtz(sc[sub][2 * kb + 1][2], sc[sub][2 * kb + 1][3]));
        u32x4 pk = {a0, a1, a2, a3};
        f16x8 pa = __builtin_bit_cast(f16x8, pk);
        accl[sub] = __builtin_amdgcn_mfma_f32_16x16x32_f16(
            pa, ones, accl[sub], 0, 0, 0);
#pragma unroll
        for (int dt = 0; dt < 4; ++dt)
          acc[sub][dt] = __builtin_amdgcn_mfma_f32_16x16x32_f16(
              pa, vf[kb][dt], acc[sub][dt], 0, 0, 0);
      }
    __builtin_amdgcn_s_setprio(0);

    __syncthreads();
    cur ^= 1;
  }

  // epilogue: linv directly from accl (row-aligned with acc, no shfl)
#pragma unroll
  for (int sub = 0; sub < 2; ++sub) {
    float linv[4];
#pragma unroll
    for (int r = 0; r < 4; ++r) linv[r] = 1.f / accl[sub][r];
    u16* op = attn_out +
              ((size_t)(b * SLEN) + q0 + (w << 5) + (sub << 4)) * HIDDEN + (h << 6);
#pragma unroll
    for (int r = 0; r < 4; ++r)
#pragma unroll
      for (int dt = 0; dt < 4; ++dt) {
        f16 hv = (f16)(acc[sub][dt][r] * linv[r]);
        op[(size_t)((lg << 2) + r) * HIDDEN + (dt << 4) + lr] = *(u16*)&hv;
      }
  }
}

// ---------------------------------------------------------------------------
extern "C" void kernel_launch(void* const* d_in, const int* in_sizes, int n_in,
                              void* d_out, int out_size, void* d_ws, size_t ws_size,
                              hipStream_t stream) {
  const float* x          = (const float*)d_in[0];
  const float* Wq         = (const float*)d_in[1];
  const float* Wk         = (const float*)d_in[2];
  const float* Wv         = (const float*)d_in[3];
  const float* Wo         = (const float*)d_in[4];
  const float* bias_table = (const float*)d_in[5];
  float* out = (float*)d_out;

  u16* xh   = (u16*)d_ws;                           // 8 MB f16 x
  u16* wt   = xh + (size_t)NROWS * HIDDEN;          // 2 MB (4 weights)
  u16* qkv  = wt + (size_t)4 * HIDDEN * HIDDEN;     // 24 MB
  u16* attno_h = qkv + (size_t)3 * NROWS * HIDDEN;  // 8 MB
  float* biasrel = (float*)(attno_h + (size_t)NROWS * HIDDEN);

  u16* qb = qkv;
  u16* kb = qkv + (size_t)NROWS * HIDDEN;
  u16* vb = qkv + (size_t)2 * NROWS * HIDDEN;   // [B,H,D,S] sigma-permuted

  bias_precompute<<<(NHEADS * RTAB + 255) / 256, 256, 0, stream>>>(bias_table, biasrel);
  conv_x<<<NROWS * HIDDEN / 8 / 256, 256, 0, stream>>>(x, xh);
  conv_w<<<dim3(HIDDEN * HIDDEN / 8 / 256, 4), 256, 0, stream>>>(Wq, Wk, Wv, Wo, wt);

  u16* wtq = wt;
  u16* wtk = wt + (size_t)HIDDEN * HIDDEN;
  u16* wtv = wt + (size_t)2 * HIDDEN * HIDDEN;
  u16* wto = wt + (size_t)3 * HIDDEN * HIDDEN;

  gemm_mfma<<<dim3(NROWS / 128, HIDDEN / 128, 3), 256, 0, stream>>>(
      xh, wtq, wtk, wtv, qkv, 1);

  flash_attn_mfma<<<SLEN / 128 * BATCH * NHEADS, 256, 0, stream>>>(
      qb, kb, vb, biasrel, attno_h);

  gemm_mfma<<<dim3(NROWS / 128, HIDDEN / 128, 1), 256, 0, stream>>>(
      attno_h, wto, wto, wto, out, 0);
}

// Round 17
// 104.844 us; speedup vs baseline: 1.7435x; 1.0009x over previous
//
#include <hip/hip_runtime.h>
#include <hip/hip_bf16.h>
#include <math.h>

#define HIDDEN 512
#define NHEADS 8
#define HDIM 64
#define SLEN 2048
#define BATCH 4
#define NROWS (BATCH*SLEN)   /* 8192 */
#define RTAB (2*SLEN-1)      /* 4095 */
#define LOG2E 1.44269504088896340736f
#define SCALE_L2E (0.125f * LOG2E)

typedef _Float16 f16;
typedef f16 f16x8 __attribute__((ext_vector_type(8)));
typedef float f32x4 __attribute__((ext_vector_type(4)));
typedef unsigned short u16;
typedef unsigned int u32;
typedef u16 u16x4 __attribute__((ext_vector_type(4)));
typedef u16 u16x8 __attribute__((ext_vector_type(8)));
typedef u32 u32x4 __attribute__((ext_vector_type(4)));

// ---------------------------------------------------------------------------
// Kernel 1: relative-position bias biasrel[h][t-s+2047], pre-scaled by log2e.
// ---------------------------------------------------------------------------
__global__ __launch_bounds__(256) void bias_precompute(
    const float* __restrict__ bias_table, float* __restrict__ biasrel) {
  int i = blockIdx.x * 256 + threadIdx.x;
  if (i >= NHEADS * RTAB) return;
  int h = i / RTAB;
  int idx = i - h * RTAB;
  int rel = idx - (SLEN - 1);
  int ret = rel > 0 ? 16 : 0;
  int a = rel < 0 ? -rel : rel;
  int bidx;
  if (a < 8) {
    bidx = a;
  } else {
    float val = logf((float)a * 0.125f) / logf(16.0f) * 8.0f;
    bidx = 8 + (int)val;
    if (bidx > 15) bidx = 15;
  }
  biasrel[i] = bias_table[(ret + bidx) * NHEADS + h] * LOG2E;
}

// ---------------------------------------------------------------------------
// Kernel 2a: x f32 -> f16
// ---------------------------------------------------------------------------
__global__ __launch_bounds__(256) void conv_x(
    const float* __restrict__ x, u16* __restrict__ xh) {
  int i = blockIdx.x * 256 + threadIdx.x;
  const float4* p = (const float4*)(x + (size_t)i * 8);
  float4 a = p[0], b = p[1];
  u16x8 o;
  f16 t0 = (f16)a.x; o[0] = *(u16*)&t0;
  f16 t1 = (f16)a.y; o[1] = *(u16*)&t1;
  f16 t2 = (f16)a.z; o[2] = *(u16*)&t2;
  f16 t3 = (f16)a.w; o[3] = *(u16*)&t3;
  f16 t4 = (f16)b.x; o[4] = *(u16*)&t4;
  f16 t5 = (f16)b.y; o[5] = *(u16*)&t5;
  f16 t6 = (f16)b.z; o[6] = *(u16*)&t6;
  f16 t7 = (f16)b.w; o[7] = *(u16*)&t7;
  *(u16x8*)(xh + (size_t)i * 8) = o;
}

// ---------------------------------------------------------------------------
// Kernel 2b: weights f32 [k][n] -> f16 transposed [n][k].
// ---------------------------------------------------------------------------
__global__ __launch_bounds__(256) void conv_w(
    const float* __restrict__ Wq, const float* __restrict__ Wk,
    const float* __restrict__ Wv, const float* __restrict__ Wo,
    u16* __restrict__ Wt) {
  const float* W = blockIdx.y == 0 ? Wq : blockIdx.y == 1 ? Wk
                 : blockIdx.y == 2 ? Wv : Wo;
  u16* dst = Wt + (size_t)blockIdx.y * HIDDEN * HIDDEN;
  int t = blockIdx.x * 256 + threadIdx.x;
  int k = t >> 6, n0 = (t & 63) << 3;
  const float4* p = (const float4*)(W + (size_t)k * HIDDEN + n0);
  float4 a = p[0], b = p[1];
  float vals[8] = {a.x, a.y, a.z, a.w, b.x, b.y, b.z, b.w};
#pragma unroll
  for (int j = 0; j < 8; ++j) {
    f16 hv = (f16)vals[j];
    dst[(size_t)(n0 + j) * HIDDEN + k] = *(u16*)&hv;
  }
}

// ---------------------------------------------------------------------------
// Kernel 3: f16 MFMA GEMM (round-11 loop). mode 0: f32 out (Wo).
// mode 1: z=0 (Q, scaled 0.125*log2e) / z=1 (K) -> f16 [B,H,S,D] via
//         LDS-transpose coalesced epilogue (round-10-proven);
//         z=2 (V) -> f16 [B,H,D,S] sigma-permuted via LDS-transpose epilogue.
// ---------------------------------------------------------------------------
__global__ __launch_bounds__(256) void gemm_mfma(
    const u16* __restrict__ A, const u16* __restrict__ Wt0,
    const u16* __restrict__ Wt1, const u16* __restrict__ Wt2,
    void* __restrict__ O, int mode) {
  __shared__ u16 sm[2 * 128 * 72];
  u16 (*As)[72] = (u16(*)[72])sm;
  u16 (*Bs)[72] = (u16(*)[72])(sm + 128 * 72);
  const u16* Wt = blockIdx.z == 0 ? Wt0 : blockIdx.z == 1 ? Wt1 : Wt2;
  const int tid = threadIdx.x;
  const int w = tid >> 6, l = tid & 63;
  const int lr = l & 15, lg = l >> 4;
  const int wr = w >> 1, wc = w & 1;
  const int m0 = blockIdx.x << 7, n0 = blockIdx.y << 7;
  const int vtmode = (mode == 1) && (blockIdx.z == 2);

  f32x4 acc[4][4] = {};

  u16x8 areg[4], breg[4];
#pragma unroll
  for (int e = 0; e < 4; ++e) {
    int c = (e << 8) + tid;
    int row = c >> 3, g = c & 7;
    areg[e] = *(const u16x8*)(A + (size_t)(m0 + row) * HIDDEN + (g << 3));
    breg[e] = *(const u16x8*)(Wt + (size_t)(n0 + row) * HIDDEN + (g << 3));
  }

  for (int k0 = 0; k0 < HIDDEN; k0 += 64) {
    __syncthreads();
#pragma unroll
    for (int e = 0; e < 4; ++e) {
      int c = (e << 8) + tid;
      int row = c >> 3, g = c & 7;
      *(u16x8*)&As[row][g << 3] = areg[e];
      *(u16x8*)&Bs[row][g << 3] = breg[e];
    }
    __syncthreads();
    if (k0 + 64 < HIDDEN) {
#pragma unroll
      for (int e = 0; e < 4; ++e) {
        int c = (e << 8) + tid;
        int row = c >> 3, g = c & 7;
        areg[e] = *(const u16x8*)(A + (size_t)(m0 + row) * HIDDEN + k0 + 64 + (g << 3));
        breg[e] = *(const u16x8*)(Wt + (size_t)(n0 + row) * HIDDEN + k0 + 64 + (g << 3));
      }
    }
#pragma unroll
    for (int kk = 0; kk < 64; kk += 32) {
      f16x8 af[4], bf[4];
#pragma unroll
      for (int mt = 0; mt < 4; ++mt)
        af[mt] = *(const f16x8*)&As[(wr << 6) + (mt << 4) + lr][kk + (lg << 3)];
#pragma unroll
      for (int nt = 0; nt < 4; ++nt)
        bf[nt] = *(const f16x8*)&Bs[(wc << 6) + (nt << 4) + lr][kk + (lg << 3)];
      if (!vtmode) {
#pragma unroll
        for (int mt = 0; mt < 4; ++mt)
#pragma unroll
          for (int nt = 0; nt < 4; ++nt)
            acc[mt][nt] = __builtin_amdgcn_mfma_f32_16x16x32_f16(
                af[mt], bf[nt], acc[mt][nt], 0, 0, 0);
      } else {
#pragma unroll
        for (int i = 0; i < 4; ++i)
#pragma unroll
          for (int j = 0; j < 4; ++j)
            acc[i][j] = __builtin_amdgcn_mfma_f32_16x16x32_f16(
                bf[i], af[j], acc[i][j], 0, 0, 0);
      }
    }
  }

  if (mode == 0) {
    float* Of = (float*)O;
#pragma unroll
    for (int mt = 0; mt < 4; ++mt)
#pragma unroll
      for (int nt = 0; nt < 4; ++nt)
#pragma unroll
        for (int r = 0; r < 4; ++r) {
          int m = m0 + (wr << 6) + (mt << 4) + (lg << 2) + r;
          int n = n0 + (wc << 6) + (nt << 4) + lr;
          Of[(size_t)m * HIDDEN + n] = acc[mt][nt][r];
        }
  } else if (!vtmode) {
    // Q/K: LDS transpose -> coalesced [B,H,S,D] u16x8 stores (round-10-proven)
    __syncthreads();
    u16* tt = sm;                           // [128][136]: [m_loc][n_loc]
    const float osc = (blockIdx.z == 0) ? SCALE_L2E : 1.0f;
#pragma unroll
    for (int mt = 0; mt < 4; ++mt)
#pragma unroll
      for (int nt = 0; nt < 4; ++nt)
#pragma unroll
        for (int r = 0; r < 4; ++r) {
          int ml = (wr << 6) + (mt << 4) + (lg << 2) + r;
          int nl = (wc << 6) + (nt << 4) + lr;
          f16 hv = (f16)(acc[mt][nt][r] * osc);
          tt[ml * 136 + nl] = *(u16*)&hv;
        }
    __syncthreads();
    u16* O16 = (u16*)O + (size_t)blockIdx.z * NROWS * HIDDEN;
    int b = m0 >> 11, s0 = m0 & (SLEN - 1);
    int hl = tid >> 7, rr = tid & 127;
    int hh = (n0 >> 6) + hl;
    u16* obase = O16 + (((size_t)b * NHEADS + hh) * SLEN + s0) * HDIM;
#pragma unroll
    for (int c = 0; c < 8; ++c) {
      int sl = (rr >> 3) + (c << 4);
      int d8 = (rr & 7) << 3;
      u16x8 v = *(const u16x8*)&tt[sl * 136 + (hl << 6) + d8];
      *(u16x8*)(obase + (size_t)sl * HDIM + d8) = v;
    }
  } else {
    __syncthreads();
    u16* tt = sm;                           // tile[128][136]: [n_loc][m_loc]
#pragma unroll
    for (int i = 0; i < 4; ++i)
#pragma unroll
      for (int j = 0; j < 4; ++j)
#pragma unroll
        for (int r = 0; r < 4; ++r) {
          int nl = (wc << 6) + (i << 4) + (lg << 2) + r;
          int ml = (wr << 6) + (j << 4) + lr;
          f16 hv = (f16)acc[i][j][r];
          tt[nl * 136 + ml] = *(u16*)&hv;
        }
    __syncthreads();
    u16* O16 = (u16*)O + (size_t)2 * NROWS * HIDDEN;
    int nl = tid >> 1, half = tid & 1;
    int n = n0 + nl;
    int h = n >> 6, d = n & 63;
    int b = m0 >> 11, s_base = m0 & (SLEN - 1);
    u16* orow = O16 + (((size_t)b * NHEADS + h) * HDIM + d) * SLEN + s_base;
    const u16* trow = tt + nl * 136;
#pragma unroll
    for (int c = 0; c < 8; ++c) {
      int v_off = (half << 6) + (c << 3);
      int c0 = (v_off & ~31) | (((v_off >> 3) & 3) << 2);
      u16x4 lo = *(const u16x4*)(trow + c0);
      u16x4 hi = *(const u16x4*)(trow + c0 + 16);
      u16x8 st;
#pragma unroll
      for (int j = 0; j < 4; ++j) { st[j] = lo[j]; st[j + 4] = hi[j]; }
      *(u16x8*)(orow + v_off) = st;
    }
  }
}

// ---------------------------------------------------------------------------
// Kernel 4: flash attention (FROZEN, round-15): single-barrier LDS dbuf,
// no-max softmax, bias in MFMA C, far-tile const bias, swapped QK^T,
// sigma-permuted V^T b128 frags, l-via-ones-MFMA.
// ---------------------------------------------------------------------------
__global__ __launch_bounds__(256) void flash_attn_mfma(
    const u16* __restrict__ qg, const u16* __restrict__ kg,
    const u16* __restrict__ vtg, const float* __restrict__ biasrel,
    u16* __restrict__ attn_out) {
  __shared__ u16 Ks[2][64][72];   // [buf][kv][d]
  __shared__ u16 Vt[2][64][72];   // [buf][d][kv] (sigma-permuted kv)

  const int tid = threadIdx.x;
  const int w = tid >> 6, l = tid & 63;
  const int lr = l & 15, lg = l >> 4;

  int bid = blockIdx.x;
  int xcd = bid & 7, idx = bid >> 3;
  int bh = (xcd << 2) + (idx >> 4);
  int bx = idx & 15;
  int h = bh & 7, b = bh >> 3;
  int q0 = bx << 7;

  const u16* qp = qg + (size_t)bh * (SLEN * HDIM);
  const u16* kp = kg + (size_t)bh * (SLEN * HDIM);
  const u16* vp = vtg + (size_t)bh * (HDIM * SLEN);

  const float bias_pos = biasrel[h * RTAB + 2 * (SLEN - 1)];
  const float bias_neg = biasrel[h * RTAB];

  f16x8 aq[2][2];
#pragma unroll
  for (int sub = 0; sub < 2; ++sub) {
    const u16* qrow = qp + (size_t)(q0 + (w << 5) + (sub << 4) + lr) * HDIM + (lg << 3);
    aq[sub][0] = *(const f16x8*)(qrow);
    aq[sub][1] = *(const f16x8*)(qrow + 32);
  }

  const float* bb = biasrel + h * RTAB + (SLEN - 1) + (lg << 2) - lr - q0 - (w << 5);

  f32x4 acc[2][4] = {};
  f32x4 accl[2] = {};
  const f16x8 ones = {(f16)1.f, (f16)1.f, (f16)1.f, (f16)1.f,
                      (f16)1.f, (f16)1.f, (f16)1.f, (f16)1.f};

  u16x8 kreg[2], vreg[2];
#pragma unroll
  for (int e = 0; e < 2; ++e) {
    int c = tid + (e << 8);
    int row = c >> 3, c8 = (c & 7) << 3;
    kreg[e] = *(const u16x8*)(kp + (size_t)row * HDIM + c8);
    vreg[e] = *(const u16x8*)(vp + (size_t)row * SLEN + c8);
  }
#pragma unroll
  for (int e = 0; e < 2; ++e) {
    int c = tid + (e << 8);
    int row = c >> 3, c8 = (c & 7) << 3;
    *(u16x8*)&Ks[0][row][c8] = kreg[e];
    *(u16x8*)&Vt[0][row][c8] = vreg[e];
  }
#pragma unroll
  for (int e = 0; e < 2; ++e) {
    int c = tid + (e << 8);
    int row = c >> 3, c8 = (c & 7) << 3;
    kreg[e] = *(const u16x8*)(kp + (size_t)(64 + row) * HDIM + c8);
    vreg[e] = *(const u16x8*)(vp + (size_t)row * SLEN + 64 + c8);
  }
  __syncthreads();

  int cur = 0;
  for (int t0 = 0; t0 < SLEN; t0 += 64) {
    if (t0 + 64 < SLEN) {
#pragma unroll
      for (int e = 0; e < 2; ++e) {
        int c = tid + (e << 8);
        int row = c >> 3, c8 = (c & 7) << 3;
        *(u16x8*)&Ks[cur ^ 1][row][c8] = kreg[e];
        *(u16x8*)&Vt[cur ^ 1][row][c8] = vreg[e];
      }
      if (t0 + 128 < SLEN) {
#pragma unroll
        for (int e = 0; e < 2; ++e) {
          int c = tid + (e << 8);
          int row = c >> 3, c8 = (c & 7) << 3;
          kreg[e] = *(const u16x8*)(kp + (size_t)(t0 + 128 + row) * HDIM + c8);
          vreg[e] = *(const u16x8*)(vp + (size_t)row * SLEN + t0 + 128 + c8);
        }
      }
    }

    int dtq = t0 - q0;
    f32x4 sc[2][4];
    if (dtq >= 256 || dtq <= -192) {
      float c = (dtq > 0) ? bias_pos : bias_neg;
      f32x4 cv = {c, c, c, c};
#pragma unroll
      for (int sub = 0; sub < 2; ++sub)
#pragma unroll
        for (int ct = 0; ct < 4; ++ct) sc[sub][ct] = cv;
    } else {
#pragma unroll
      for (int sub = 0; sub < 2; ++sub)
#pragma unroll
        for (int ct = 0; ct < 4; ++ct)
#pragma unroll
          for (int r = 0; r < 4; ++r)
            sc[sub][ct][r] = bb[t0 + (ct << 4) + r - (sub << 4)];
    }

    f16x8 kf[4][2];
#pragma unroll
    for (int ct = 0; ct < 4; ++ct) {
      kf[ct][0] = *(const f16x8*)&Ks[cur][(ct << 4) + lr][lg << 3];
      kf[ct][1] = *(const f16x8*)&Ks[cur][(ct << 4) + lr][32 + (lg << 3)];
    }

    __builtin_amdgcn_s_setprio(1);
#pragma unroll
    for (int sub = 0; sub < 2; ++sub)
#pragma unroll
      for (int ct = 0; ct < 4; ++ct) {
        sc[sub][ct] = __builtin_amdgcn_mfma_f32_16x16x32_f16(
            kf[ct][0], aq[sub][0], sc[sub][ct], 0, 0, 0);
        sc[sub][ct] = __builtin_amdgcn_mfma_f32_16x16x32_f16(
            kf[ct][1], aq[sub][1], sc[sub][ct], 0, 0, 0);
      }
    __builtin_amdgcn_s_setprio(0);

#pragma unroll
    for (int sub = 0; sub < 2; ++sub)
#pragma unroll
      for (int ct = 0; ct < 4; ++ct)
#pragma unroll
        for (int r = 0; r < 4; ++r)
          sc[sub][ct][r] = __builtin_amdgcn_exp2f(sc[sub][ct][r]);

    f16x8 vf[2][4];
#pragma unroll
    for (int kb = 0; kb < 2; ++kb)
#pragma unroll
      for (int dt = 0; dt < 4; ++dt)
        vf[kb][dt] = *(const f16x8*)&Vt[cur][(dt << 4) + lr][(kb << 5) + (lg << 3)];

    __builtin_amdgcn_s_setprio(1);
#pragma unroll
    for (int sub = 0; sub < 2; ++sub)
#pragma unroll
      for (int kb = 0; kb < 2; ++kb) {
        u32 a0 = __builtin_bit_cast(u32,
            __builtin_amdgcn_cvt_pkrtz(sc[sub][2 * kb][0], sc[sub][2 * kb][1]));
        u32 a1 = __builtin_bit_cast(u32,
            __builtin_amdgcn_cvt_pkrtz(sc[sub][2 * kb][2], sc[sub][2 * kb][3]));
        u32 a2 = __builtin_bit_cast(u32,
            __builtin_amdgcn_cvt_pkrtz(sc[sub][2 * kb + 1][0], sc[sub][2 * kb + 1][1]));
        u32 a3 = __builtin_bit_cast(u32,
            __builtin_amdgcn_cvt_pkrtz(sc[sub][2 * kb + 1][2], sc[sub][2 * kb + 1][3]));
        u32x4 pk = {a0, a1, a2, a3};
        f16x8 pa = __builtin_bit_cast(f16x8, pk);
        accl[sub] = __builtin_amdgcn_mfma_f32_16x16x32_f16(
            pa, ones, accl[sub], 0, 0, 0);
#pragma unroll
        for (int dt = 0; dt < 4; ++dt)
          acc[sub][dt] = __builtin_amdgcn_mfma_f32_16x16x32_f16(
              pa, vf[kb][dt], acc[sub][dt], 0, 0, 0);
      }
    __builtin_amdgcn_s_setprio(0);

    __syncthreads();
    cur ^= 1;
  }

#pragma unroll
  for (int sub = 0; sub < 2; ++sub) {
    float linv[4];
#pragma unroll
    for (int r = 0; r < 4; ++r) linv[r] = 1.f / accl[sub][r];
    u16* op = attn_out +
              ((size_t)(b * SLEN) + q0 + (w << 5) + (sub << 4)) * HIDDEN + (h << 6);
#pragma unroll
    for (int r = 0; r < 4; ++r)
#pragma unroll
      for (int dt = 0; dt < 4; ++dt) {
        f16 hv = (f16)(acc[sub][dt][r] * linv[r]);
        op[(size_t)((lg << 2) + r) * HIDDEN + (dt << 4) + lr] = *(u16*)&hv;
      }
  }
}

// ---------------------------------------------------------------------------
extern "C" void kernel_launch(void* const* d_in, const int* in_sizes, int n_in,
                              void* d_out, int out_size, void* d_ws, size_t ws_size,
                              hipStream_t stream) {
  const float* x          = (const float*)d_in[0];
  const float* Wq         = (const float*)d_in[1];
  const float* Wk         = (const float*)d_in[2];
  const float* Wv         = (const float*)d_in[3];
  const float* Wo         = (const float*)d_in[4];
  const float* bias_table = (const float*)d_in[5];
  float* out = (float*)d_out;

  u16* xh   = (u16*)d_ws;                           // 8 MB f16 x
  u16* wt   = xh + (size_t)NROWS * HIDDEN;          // 2 MB (4 weights)
  u16* qkv  = wt + (size_t)4 * HIDDEN * HIDDEN;     // 24 MB
  u16* attno_h = qkv + (size_t)3 * NROWS * HIDDEN;  // 8 MB
  float* biasrel = (float*)(attno_h + (size_t)NROWS * HIDDEN);

  u16* qb = qkv;
  u16* kb = qkv + (size_t)NROWS * HIDDEN;
  u16* vb = qkv + (size_t)2 * NROWS * HIDDEN;   // [B,H,D,S] sigma-permuted

  bias_precompute<<<(NHEADS * RTAB + 255) / 256, 256, 0, stream>>>(bias_table, biasrel);
  conv_x<<<NROWS * HIDDEN / 8 / 256, 256, 0, stream>>>(x, xh);
  conv_w<<<dim3(HIDDEN * HIDDEN / 8 / 256, 4), 256, 0, stream>>>(Wq, Wk, Wv, Wo, wt);

  u16* wtq = wt;
  u16* wtk = wt + (size_t)HIDDEN * HIDDEN;
  u16* wtv = wt + (size_t)2 * HIDDEN * HIDDEN;
  u16* wto = wt + (size_t)3 * HIDDEN * HIDDEN;

  gemm_mfma<<<dim3(NROWS / 128, HIDDEN / 128, 3), 256, 0, stream>>>(
      xh, wtq, wtk, wtv, qkv, 1);

  flash_attn_mfma<<<SLEN / 128 * BATCH * NHEADS, 256, 0, stream>>>(
      qb, kb, vb, biasrel, attno_h);

  gemm_mfma<<<dim3(NROWS / 128, HIDDEN / 128, 1), 256, 0, stream>>>(
      attno_h, wto, wto, wto, out, 0);
}